// Round 1
// baseline (128.376 us; speedup 1.0000x reference)
//
#include <hip/hip_runtime.h>

// CrossAttentionBlock, collapsed form:
//   softmax over a single KV token == 1.0  =>  attn output per (b,s) = v[b] (C-vector)
//   a[b] = (text_emb[b] @ Wv.T) @ Wo.T + bo          (per-batch, s-independent)
//   y[b,c,s] = LN_c(x[b,c,s] + a[b,c]) * gamma[c] + beta[c]   (LN over C per (b,s))
// Wq, Wk are dead.

constexpr int B = 16, C = 512, T = 768, S = 4096;
constexpr int TS = 32;    // spatial positions per tile
constexpr int BLK = 256;  // threads in fused_ln block
constexpr float LN_EPS = 1e-5f;

// ---------------- kernel 1: a[b][c] = (te[b] @ Wv.T) @ Wo.T + bo ----------------
__global__ __launch_bounds__(512) void prep_attn(const float* __restrict__ te,
                                                 const float* __restrict__ Wv,
                                                 const float* __restrict__ Wo,
                                                 const float* __restrict__ bo,
                                                 float* __restrict__ a_out) {
    __shared__ float te_s[T];
    __shared__ float v_s[C];
    const int b = blockIdx.x;
    for (int t = threadIdx.x; t < T; t += 512) te_s[t] = te[b * T + t];
    __syncthreads();

    const int c = threadIdx.x;  // 512 threads, one output channel each
    float acc = 0.f;
    const float4* wr  = reinterpret_cast<const float4*>(Wv + (size_t)c * T);
    const float4* ts4 = reinterpret_cast<const float4*>(te_s);
#pragma unroll 4
    for (int t = 0; t < T / 4; ++t) {
        float4 w4 = wr[t]; float4 t4 = ts4[t];
        acc += w4.x * t4.x + w4.y * t4.y + w4.z * t4.z + w4.w * t4.w;
    }
    v_s[c] = acc;
    __syncthreads();

    float acc2 = bo[c];
    const float4* wo4 = reinterpret_cast<const float4*>(Wo + (size_t)c * C);
    const float4* vs4 = reinterpret_cast<const float4*>(v_s);
#pragma unroll 4
    for (int t = 0; t < C / 4; ++t) {
        float4 w4 = wo4[t]; float4 v4 = vs4[t];
        acc2 += w4.x * v4.x + w4.y * v4.y + w4.z * v4.z + w4.w * v4.w;
    }
    a_out[b * C + c] = acc2;
}

// ---------------- kernel 2: fused broadcast-add + LayerNorm over C ----------------
// grid: B * S/TS blocks; each block owns (b, s0..s0+31), all 512 channels.
__global__ __launch_bounds__(BLK) void fused_ln(const float* __restrict__ x,
                                                const float* __restrict__ a,
                                                const float* __restrict__ gamma,
                                                const float* __restrict__ beta,
                                                float* __restrict__ out) {
    __shared__ float tile[C * TS];            // 64 KB, tile[c*32 + s]
    __shared__ float a_s[C], g_s[C], be_s[C]; // 6 KB
    __shared__ float psum[8 * TS], psq[8 * TS];
    __shared__ float mean_s[TS], rstd_s[TS];

    const int bid = blockIdx.x;
    const int b   = bid >> 7;            // / (S/TS = 128)
    const int s0  = (bid & 127) << 5;    // * 32
    const int tid = threadIdx.x;

    // preload per-channel vectors
    for (int c = tid; c < C; c += BLK) {
        a_s[c]  = a[b * C + c];
        g_s[c]  = gamma[c];
        be_s[c] = beta[c];
    }

    // stage x tile: coalesced float4 along s (8 lanes cover one 128B row segment)
    const float* xb = x + (size_t)b * C * S + s0;
#pragma unroll
    for (int j = 0; j < 16; ++j) {
        int idx = j * BLK + tid;          // float4 index 0..4095
        int c   = idx >> 3;               // 8 float4 per row
        int p   = (idx & 7) << 2;         // float offset within row
        float4 v = *reinterpret_cast<const float4*>(xb + (size_t)c * S + p);
        *reinterpret_cast<float4*>(tile + c * TS + p) = v;
    }
    __syncthreads();

    const int w    = tid >> 6;   // wave 0..3 -> c-range of 128
    const int l    = tid & 63;
    const int s    = l & 31;     // spatial position owned by this lane
    const int sub  = l >> 5;     // which 64-channel half of the wave's range
    const int cbase = w * 128 + sub * 64;

    // partial sum / sumsq over this lane's 64 channels
    float sum = 0.f, sq = 0.f;
#pragma unroll 4
    for (int i = 0; i < 64; ++i) {
        int c = cbase + i;
        float v = tile[c * TS + s] + a_s[c];
        sum += v; sq += v * v;
    }
    psum[(w * 2 + sub) * TS + s] = sum;
    psq [(w * 2 + sub) * TS + s] = sq;
    __syncthreads();

    if (tid < TS) {
        float tsum = 0.f, tsq = 0.f;
#pragma unroll
        for (int j = 0; j < 8; ++j) { tsum += psum[j * TS + tid]; tsq += psq[j * TS + tid]; }
        float mu  = tsum * (1.f / C);
        float var = tsq * (1.f / C) - mu * mu;
        mean_s[tid] = mu;
        rstd_s[tid] = rsqrtf(var + LN_EPS);
    }
    __syncthreads();

    float* ob = out + (size_t)b * C * S + s0;
    const float mu = mean_s[s];
    const float rs = rstd_s[s];
#pragma unroll 4
    for (int i = 0; i < 64; ++i) {
        int c = cbase + i;
        float v = tile[c * TS + s] + a_s[c];
        ob[(size_t)c * S + s] = (v - mu) * rs * g_s[c] + be_s[c];
    }
}

extern "C" void kernel_launch(void* const* d_in, const int* in_sizes, int n_in,
                              void* d_out, int out_size, void* d_ws, size_t ws_size,
                              hipStream_t stream) {
    const float* x     = (const float*)d_in[0];
    const float* te    = (const float*)d_in[1];
    // d_in[2] = Wq, d_in[3] = Wk: dead (softmax over single KV token == 1)
    const float* Wv    = (const float*)d_in[4];
    const float* Wo    = (const float*)d_in[5];
    const float* bo    = (const float*)d_in[6];
    const float* gamma = (const float*)d_in[7];
    const float* beta  = (const float*)d_in[8];
    float* out = (float*)d_out;
    float* a   = (float*)d_ws;   // 16*512 floats = 32 KB scratch

    prep_attn<<<B, 512, 0, stream>>>(te, Wv, Wo, bo, a);
    fused_ln<<<B * (S / TS), BLK, 0, stream>>>(x, a, gamma, beta, out);
}

// Round 2
// 59.084 us; speedup vs baseline: 2.1728x; 2.1728x over previous
//
#include <hip/hip_runtime.h>

// CrossAttentionBlock, collapsed form:
//   softmax over a single KV token == 1.0  =>  attn output per (b,s) = v[b] (C-vector)
//   a[b] = (text_emb[b] @ Wv.T) @ Wo.T + bo          (per-batch, s-independent)
//   y[b,c,s] = LN_c(x[b,c,s] + a[b,c]) * gamma[c] + beta[c]   (LN over C per (b,s))
// Wq, Wk are dead.

constexpr int B = 16, C = 512, T = 768, S = 4096;
constexpr int TS = 32;    // spatial positions per tile
constexpr int BLK = 256;  // threads in fused_ln block
constexpr float LN_EPS = 1e-5f;

// ---------------- wave-per-output GEMV: out[b][c] = row_b(in) . row_c(Wt) + bias[c] ----
// K = reduction length (multiple of 256). grid = B*C/4 blocks of 256 (4 waves).
template <int K, bool HAS_BIAS>
__global__ __launch_bounds__(256) void gemv_wave(const float* __restrict__ in,
                                                 const float* __restrict__ Wt,
                                                 const float* __restrict__ bias,
                                                 float* __restrict__ out) {
    const int w    = blockIdx.x * 4 + (threadIdx.x >> 6);
    const int lane = threadIdx.x & 63;
    const int b    = w >> 9;          // / C
    const int c    = w & (C - 1);
    const float4* wr = reinterpret_cast<const float4*>(Wt + (size_t)c * K);
    const float4* xr = reinterpret_cast<const float4*>(in + (size_t)b * K);
    float acc = 0.f;
#pragma unroll
    for (int i = lane; i < K / 4; i += 64) {
        float4 a = wr[i], t = xr[i];
        acc += a.x * t.x + a.y * t.y + a.z * t.z + a.w * t.w;
    }
#pragma unroll
    for (int off = 32; off > 0; off >>= 1) acc += __shfl_down(acc, off);
    if (lane == 0) out[b * C + c] = HAS_BIAS ? acc + bias[c] : acc;
}

// ---------------- fused broadcast-add + LayerNorm over C ----------------
// grid: B * S/TS blocks; each block owns (b, s0..s0+31), all 512 channels.
__global__ __launch_bounds__(BLK) void fused_ln(const float* __restrict__ x,
                                                const float* __restrict__ a,
                                                const float* __restrict__ gamma,
                                                const float* __restrict__ beta,
                                                float* __restrict__ out) {
    __shared__ float tile[C * TS];            // 64 KB, tile[c*32 + s]
    __shared__ float a_s[C], g_s[C], be_s[C]; // 6 KB
    __shared__ float psum[8 * TS], psq[8 * TS];
    __shared__ float mean_s[TS], rstd_s[TS];

    const int bid = blockIdx.x;
    const int b   = bid >> 7;            // / (S/TS = 128)
    const int s0  = (bid & 127) << 5;    // * 32
    const int tid = threadIdx.x;

    // preload per-channel vectors
    for (int c = tid; c < C; c += BLK) {
        a_s[c]  = a[b * C + c];
        g_s[c]  = gamma[c];
        be_s[c] = beta[c];
    }

    // stage x tile: coalesced float4 along s (8 lanes cover one 128B row segment)
    const float* xb = x + (size_t)b * C * S + s0;
#pragma unroll
    for (int j = 0; j < 16; ++j) {
        int idx = j * BLK + tid;          // float4 index 0..4095
        int c   = idx >> 3;               // 8 float4 per row
        int p   = (idx & 7) << 2;         // float offset within row
        float4 v = *reinterpret_cast<const float4*>(xb + (size_t)c * S + p);
        *reinterpret_cast<float4*>(tile + c * TS + p) = v;
    }
    __syncthreads();

    const int w    = tid >> 6;   // wave 0..3 -> c-range of 128
    const int l    = tid & 63;
    const int s    = l & 31;     // spatial position owned by this lane
    const int sub  = l >> 5;     // which 64-channel half of the wave's range
    const int cbase = w * 128 + sub * 64;

    // partial sum / sumsq over this lane's 64 channels
    float sum = 0.f, sq = 0.f;
#pragma unroll 4
    for (int i = 0; i < 64; ++i) {
        int c = cbase + i;
        float v = tile[c * TS + s] + a_s[c];
        sum += v; sq += v * v;
    }
    psum[(w * 2 + sub) * TS + s] = sum;
    psq [(w * 2 + sub) * TS + s] = sq;
    __syncthreads();

    if (tid < TS) {
        float tsum = 0.f, tsq = 0.f;
#pragma unroll
        for (int j = 0; j < 8; ++j) { tsum += psum[j * TS + tid]; tsq += psq[j * TS + tid]; }
        float mu  = tsum * (1.f / C);
        float var = tsq * (1.f / C) - mu * mu;
        mean_s[tid] = mu;
        rstd_s[tid] = rsqrtf(var + LN_EPS);
    }
    __syncthreads();

    float* ob = out + (size_t)b * C * S + s0;
    const float mu = mean_s[s];
    const float rs = rstd_s[s];
#pragma unroll 4
    for (int i = 0; i < 64; ++i) {
        int c = cbase + i;
        float v = tile[c * TS + s] + a_s[c];
        ob[(size_t)c * S + s] = (v - mu) * rs * g_s[c] + be_s[c];
    }
}

extern "C" void kernel_launch(void* const* d_in, const int* in_sizes, int n_in,
                              void* d_out, int out_size, void* d_ws, size_t ws_size,
                              hipStream_t stream) {
    const float* x     = (const float*)d_in[0];
    const float* te    = (const float*)d_in[1];
    // d_in[2] = Wq, d_in[3] = Wk: dead (softmax over single KV token == 1)
    const float* Wv    = (const float*)d_in[4];
    const float* Wo    = (const float*)d_in[5];
    const float* bo    = (const float*)d_in[6];
    const float* gamma = (const float*)d_in[7];
    const float* beta  = (const float*)d_in[8];
    float* out = (float*)d_out;
    float* v   = (float*)d_ws;              // 16*512 floats
    float* a   = (float*)d_ws + B * C;      // 16*512 floats

    gemv_wave<T, false><<<B * C / 4, 256, 0, stream>>>(te, Wv, nullptr, v);
    gemv_wave<C, true ><<<B * C / 4, 256, 0, stream>>>(v,  Wo, bo,      a);
    fused_ln<<<B * (S / TS), BLK, 0, stream>>>(x, a, gamma, beta, out);
}